// Round 15
// baseline (22.326 us; speedup 1.0000x reference)
//
#include <hip/hip_runtime.h>
#include <hip/hip_bf16.h>

// MSAColumnAttention fully-fused SINGLE-dispatch kernel for MI355X (gfx950).
// S=64, I=128, C=64, D=32, H=8, F=256. Grid 128 = one block per residue i,
// 1024 thr (16 waves x 16 features). R15 = R14 with ALL global loads (msa,
// Wqkv, Wg, Wout, bout) hoisted to the top: one cold-miss generation, every
// HBM latency overlapped. Body: LN -> QKVG MFMA acc[mt][sec] -> in-register
// poly-softmax (moments + xor16/32 butterfly + Horner) -> out-proj K=256 ->
// direct store + bias. No d_ws, no atomics, no memset, one dispatch.

typedef __attribute__((ext_vector_type(8))) short bf16x8;
typedef __attribute__((ext_vector_type(4))) float f32x4;

__device__ __forceinline__ unsigned short f2bf(float f) {
    __hip_bfloat16 h = __float2bfloat16(f);           // RNE
    return *reinterpret_cast<unsigned short*>(&h);
}
__device__ __forceinline__ bf16x8 pack8(const float* t) {
    union { unsigned short u[8]; bf16x8 v8; } pk;
    #pragma unroll
    for (int j = 0; j < 8; ++j) pk.u[j] = f2bf(t[j]);
    return pk.v8;
}

__global__ __launch_bounds__(1024, 1) void msa_col_attn_fused(
    const float* __restrict__ msa,   // [64,128,64]
    const float* __restrict__ ln_s,  // [64]
    const float* __restrict__ ln_b,  // [64]
    const float* __restrict__ Wqkv,  // [64,768]
    const float* __restrict__ Wg,    // [64,256]
    const float* __restrict__ Wout,  // [256,64]
    const float* __restrict__ bout,  // [64]
    float* __restrict__ out)         // [64,128,64]
{
    // XF: X A-frags [2kt][4mt][64][8] = 8192B.
    // XFo: attn-out A-frags [8kt][4mt][64][8] = 32768B (K=256).
    __shared__ __align__(16) char smem[8192 + 32768];
    unsigned short* XF  = (unsigned short*)smem;
    unsigned short* XFo = (unsigned short*)(smem + 8192);

    const int tid  = threadIdx.x;
    const int i    = blockIdx.x;     // residue
    const int l    = tid & 63;
    const int wv   = tid >> 6;       // wave id 0..15 (uniform)
    const int lg   = l >> 4;
    const int ln16 = l & 15;
    const int f    = wv * 16 + ln16; // this lane's feature (QKVG phase)
    const int mt4  = wv & 3, nn2 = wv >> 2;
    const int cc   = nn2 * 16 + ln16;

    // ======== ONE cold-miss generation: issue ALL global loads now ========
    // msa (waves 0-7 consume in LN)
    const int sL = tid >> 3;
    const int c0 = (tid & 7) * 8;
    const float* rowp = msa + ((sL & 63) * 128 + i) * 64 + c0;
    float4 m0, m1;
    if (wv < 8) { m0 = *(const float4*)(rowp); m1 = *(const float4*)(rowp + 4); }

    // QKVG W gathers
    float wqg[4][2][8];   // [sec][kt][j]
    #pragma unroll
    for (int sec = 0; sec < 4; ++sec)
        #pragma unroll
        for (int kt = 0; kt < 2; ++kt)
            #pragma unroll
            for (int j = 0; j < 8; ++j) {
                const int r = kt * 32 + lg * 8 + j;
                wqg[sec][kt][j] = (sec == 3) ? Wg[r * 256 + f]
                                             : Wqkv[r * 768 + sec * 256 + f];
            }

    // Wout gathers (consumed by out-proj at the end)
    float wo[8][8];   // [kt][j]
    #pragma unroll
    for (int kt = 0; kt < 8; ++kt)
        #pragma unroll
        for (int j = 0; j < 8; ++j)
            wo[kt][j] = Wout[(kt * 32 + lg * 8 + j) * 64 + cc];

    // bias
    const float bb = bout[cc];

    // ---- waves 0-7: LayerNorm -> X A-fragments ----
    if (wv < 8) {
        float v[8] = {m0.x, m0.y, m0.z, m0.w, m1.x, m1.y, m1.z, m1.w};
        float sum = 0.f, sq = 0.f;
        #pragma unroll
        for (int j = 0; j < 8; ++j) { sum += v[j]; sq += v[j] * v[j]; }
        sum += __shfl_xor(sum, 1);  sq += __shfl_xor(sq, 1);
        sum += __shfl_xor(sum, 2);  sq += __shfl_xor(sq, 2);
        sum += __shfl_xor(sum, 4);  sq += __shfl_xor(sq, 4);
        const float mu  = sum * (1.f / 64.f);
        const float var = sq * (1.f / 64.f) - mu * mu;
        const float rs  = __builtin_amdgcn_rsqf(var + 1e-5f);
        const float4 s0 = *(const float4*)(ln_s + c0);
        const float4 s1 = *(const float4*)(ln_s + c0 + 4);
        const float4 b0 = *(const float4*)(ln_b + c0);
        const float4 b1 = *(const float4*)(ln_b + c0 + 4);
        const float sc[8] = {s0.x,s0.y,s0.z,s0.w,s1.x,s1.y,s1.z,s1.w};
        const float bi[8] = {b0.x,b0.y,b0.z,b0.w,b1.x,b1.y,b1.z,b1.w};
        float t[8];
        #pragma unroll
        for (int j = 0; j < 8; ++j) t[j] = (v[j] - mu) * rs * sc[j] + bi[j];
        const int kt = c0 >> 5, g = (c0 >> 3) & 3, mt = sL >> 4;
        *(bf16x8*)(XF + (((kt * 4 + mt) * 64) + g * 16 + (sL & 15)) * 8) = pack8(t);
    }

    // pack QKVG W frags (q-scale folded) while LN finishes
    bf16x8 bfr[4][2];   // [sec][kt]
    #pragma unroll
    for (int kt = 0; kt < 2; ++kt) {
        float t0[8];
        #pragma unroll
        for (int j = 0; j < 8; ++j) t0[j] = wqg[0][kt][j] * 0.17677670f;  // 1/sqrt(32)
        bfr[0][kt] = pack8(t0);
        bfr[1][kt] = pack8(wqg[1][kt]);
        bfr[2][kt] = pack8(wqg[2][kt]);
        bfr[3][kt] = pack8(wqg[3][kt]);
    }
    // pack Wout frags early too (loads issued at top have landed); wo dies here
    bf16x8 ofr[8];
    #pragma unroll
    for (int kt = 0; kt < 8; ++kt) ofr[kt] = pack8(wo[kt]);
    __syncthreads();

    // ---------------- QKVG MFMA: acc[mt][sec], rows = x-row (s or t) --------
    f32x4 acc[4][4];
    #pragma unroll
    for (int mt = 0; mt < 4; ++mt)
        #pragma unroll
        for (int sec = 0; sec < 4; ++sec) acc[mt][sec] = (f32x4){0.f, 0.f, 0.f, 0.f};
    #pragma unroll
    for (int kt = 0; kt < 2; ++kt)
        #pragma unroll
        for (int mt = 0; mt < 4; ++mt) {
            const bf16x8 a = *(const bf16x8*)(XF + ((kt * 4 + mt) * 64 + l) * 8);
            #pragma unroll
            for (int sec = 0; sec < 4; ++sec)
                acc[mt][sec] = __builtin_amdgcn_mfma_f32_16x16x32_bf16(
                    a, bfr[sec][kt], acc[mt][sec], 0, 0, 0);
        }

    // ---------------- register-resident attention (all lanes useful) --------
    // lane's feature f. acc rows: idx = mt*16 + lg*4 + r.
    // k = acc[.][1], v = acc[.][2] -> 16 t-partials; xor16/32 butterfly sums
    // all 64 t. q = acc[.][0] (pre-scaled), g = acc[.][3] -> 16 s outputs.
    {
        float L1 = 0.f, L2 = 0.f, L3 = 0.f, L4 = 0.f;
        float M0 = 0.f, M1 = 0.f, M2 = 0.f, M3 = 0.f, M4 = 0.f;
        #pragma unroll
        for (int mt = 0; mt < 4; ++mt)
            #pragma unroll
            for (int r = 0; r < 4; ++r) {
                const float k1 = acc[mt][1][r];
                const float vv = acc[mt][2][r];
                const float k2 = k1 * k1;
                const float k3 = k2 * k1;
                const float k4 = k2 * k2;
                L1 += k1; L2 += k2; L3 += k3; L4 += k4;
                M0 += vv;
                M1 = fmaf(k1, vv, M1);
                M2 = fmaf(k2, vv, M2);
                M3 = fmaf(k3, vv, M3);
                M4 = fmaf(k4, vv, M4);
            }
        #pragma unroll
        for (int m = 16; m <= 32; m <<= 1) {
            L1 += __shfl_xor(L1, m); L2 += __shfl_xor(L2, m);
            L3 += __shfl_xor(L3, m); L4 += __shfl_xor(L4, m);
            M0 += __shfl_xor(M0, m); M1 += __shfl_xor(M1, m);
            M2 += __shfl_xor(M2, m); M3 += __shfl_xor(M3, m);
            M4 += __shfl_xor(M4, m);
        }
        const float a4 = L4 * (1.f / 24.f), a3 = L3 * (1.f / 6.f), a2 = L2 * 0.5f;
        const float b4 = M4 * (1.f / 24.f), b3 = M3 * (1.f / 6.f), b2 = M2 * 0.5f;

        // XFo A-frag coords for feature f: kt2 = wv>>1, g2 = (wv&1)*2+(ln16>>3),
        // jj = ln16&7  (f = kt2*32 + g2*8 + jj).
        const int kt2 = wv >> 1;
        const int g2  = (wv & 1) * 2 + (ln16 >> 3);
        const int jj  = ln16 & 7;
        #pragma unroll
        for (int mt = 0; mt < 4; ++mt)
            #pragma unroll
            for (int r = 0; r < 4; ++r) {
                const float qv = acc[mt][0][r];
                const float gv = __builtin_amdgcn_rcpf(
                    1.f + __builtin_amdgcn_exp2f(acc[mt][3][r] * -1.44269504f));
                const float den = fmaf(fmaf(fmaf(fmaf(a4, qv, a3), qv, a2), qv, L1), qv, 64.f);
                const float num = fmaf(fmaf(fmaf(fmaf(b4, qv, b3), qv, b2), qv, M1), qv, M0);
                const float o   = gv * num * __builtin_amdgcn_rcpf(den);
                XFo[((kt2 * 4 + mt) * 64 + g2 * 16 + lg * 4 + r) * 8 + jj] = f2bf(o);
            }
    }
    __syncthreads();

    // ---------------- out-proj (K=256) -> direct store + bias ----------------
    // wave -> (mt4 s-block, nn2 c-tile of 16). 8 kt MFMAs.
    {
        f32x4 a2v = (f32x4){0.f, 0.f, 0.f, 0.f};
        #pragma unroll
        for (int kt = 0; kt < 8; ++kt) {
            const bf16x8 afr = *(const bf16x8*)(XFo + ((kt * 4 + mt4) * 64 + l) * 8);
            a2v = __builtin_amdgcn_mfma_f32_16x16x32_bf16(afr, ofr[kt], a2v, 0, 0, 0);
        }
        #pragma unroll
        for (int r = 0; r < 4; ++r) {
            const int s = mt4 * 16 + lg * 4 + r;
            out[(s * 128 + i) * 64 + cc] = a2v[r] + bb;
        }
    }
}

extern "C" void kernel_launch(void* const* d_in, const int* in_sizes, int n_in,
                              void* d_out, int out_size, void* d_ws, size_t ws_size,
                              hipStream_t stream) {
    (void)in_sizes; (void)n_in; (void)d_ws; (void)ws_size; (void)out_size;
    const float* msa  = (const float*)d_in[0];
    const float* ln_s = (const float*)d_in[1];
    const float* ln_b = (const float*)d_in[2];
    const float* Wqkv = (const float*)d_in[3];
    const float* Wg   = (const float*)d_in[4];
    const float* Wout = (const float*)d_in[5];
    const float* bout = (const float*)d_in[6];
    float* out = (float*)d_out;

    msa_col_attn_fused<<<dim3(128), dim3(1024), 0, stream>>>(
        msa, ln_s, ln_b, Wqkv, Wg, Wout, bout, out);
}

// Round 16
// 15.841 us; speedup vs baseline: 1.4094x; 1.4094x over previous
//
#include <hip/hip_runtime.h>
#include <hip/hip_bf16.h>

// MSAColumnAttention fully-fused SINGLE-dispatch kernel for MI355X (gfx950).
// S=64, I=128, C=64, D=32, H=8, F=256. Grid 128 = one block per residue i,
// 1024 thr (16 waves x 16 features). R16 = exact revert to R14 (best: 16.1us).
//   - 64 scattered QKVG W dwords issued BEFORE LN (hide under msa+LN+barrier)
//   - QKVG MFMA: acc[mt][sec] for sec in {q,k,v,g} (all lanes useful)
//   - 64 Wout dwords issued after QKVG MFMA (hide under attention)
//   - in-register poly-softmax: moments L_n,M_n + xor16/32 butterfly, Horner
//   - out-proj K=256 in-block -> DIRECT store + bias.
// No d_ws, no second dispatch, no atomics, no memset.
// (R15's hoist-everything variant spilled: wqg+wo simultaneously live -> 22.3us.)

typedef __attribute__((ext_vector_type(8))) short bf16x8;
typedef __attribute__((ext_vector_type(4))) float f32x4;

__device__ __forceinline__ unsigned short f2bf(float f) {
    __hip_bfloat16 h = __float2bfloat16(f);           // RNE
    return *reinterpret_cast<unsigned short*>(&h);
}
__device__ __forceinline__ bf16x8 pack8(const float* t) {
    union { unsigned short u[8]; bf16x8 v8; } pk;
    #pragma unroll
    for (int j = 0; j < 8; ++j) pk.u[j] = f2bf(t[j]);
    return pk.v8;
}

__global__ __launch_bounds__(1024, 1) void msa_col_attn_fused(
    const float* __restrict__ msa,   // [64,128,64]
    const float* __restrict__ ln_s,  // [64]
    const float* __restrict__ ln_b,  // [64]
    const float* __restrict__ Wqkv,  // [64,768]
    const float* __restrict__ Wg,    // [64,256]
    const float* __restrict__ Wout,  // [256,64]
    const float* __restrict__ bout,  // [64]
    float* __restrict__ out)         // [64,128,64]
{
    // XF: X A-frags [2kt][4mt][64][8] = 8192B.
    // XFo: attn-out A-frags [8kt][4mt][64][8] = 32768B (K=256).
    __shared__ __align__(16) char smem[8192 + 32768];
    unsigned short* XF  = (unsigned short*)smem;
    unsigned short* XFo = (unsigned short*)(smem + 8192);

    const int tid  = threadIdx.x;
    const int i    = blockIdx.x;     // residue
    const int l    = tid & 63;
    const int wv   = tid >> 6;       // wave id 0..15 (uniform)
    const int lg   = l >> 4;
    const int ln16 = l & 15;
    const int f    = wv * 16 + ln16; // this lane's feature (QKVG phase)

    // ---- issue msa loads first (waves 0-7 consume in LN) ----
    const int sL = tid >> 3;
    const int c0 = (tid & 7) * 8;
    const float* rowp = msa + ((sL & 63) * 128 + i) * 64 + c0;
    float4 m0, m1;
    if (wv < 8) { m0 = *(const float4*)(rowp); m1 = *(const float4*)(rowp + 4); }

    // ---- issue QKVG W gathers (latency hides under msa+LN+barrier) ----
    float wqg[4][2][8];   // [sec][kt][j]
    #pragma unroll
    for (int sec = 0; sec < 4; ++sec)
        #pragma unroll
        for (int kt = 0; kt < 2; ++kt)
            #pragma unroll
            for (int j = 0; j < 8; ++j) {
                const int r = kt * 32 + lg * 8 + j;
                wqg[sec][kt][j] = (sec == 3) ? Wg[r * 256 + f]
                                             : Wqkv[r * 768 + sec * 256 + f];
            }

    // ---- waves 0-7: LayerNorm -> X A-fragments ----
    if (wv < 8) {
        float v[8] = {m0.x, m0.y, m0.z, m0.w, m1.x, m1.y, m1.z, m1.w};
        float sum = 0.f, sq = 0.f;
        #pragma unroll
        for (int j = 0; j < 8; ++j) { sum += v[j]; sq += v[j] * v[j]; }
        sum += __shfl_xor(sum, 1);  sq += __shfl_xor(sq, 1);
        sum += __shfl_xor(sum, 2);  sq += __shfl_xor(sq, 2);
        sum += __shfl_xor(sum, 4);  sq += __shfl_xor(sq, 4);
        const float mu  = sum * (1.f / 64.f);
        const float var = sq * (1.f / 64.f) - mu * mu;
        const float rs  = __builtin_amdgcn_rsqf(var + 1e-5f);
        const float4 s0 = *(const float4*)(ln_s + c0);
        const float4 s1 = *(const float4*)(ln_s + c0 + 4);
        const float4 b0 = *(const float4*)(ln_b + c0);
        const float4 b1 = *(const float4*)(ln_b + c0 + 4);
        const float sc[8] = {s0.x,s0.y,s0.z,s0.w,s1.x,s1.y,s1.z,s1.w};
        const float bi[8] = {b0.x,b0.y,b0.z,b0.w,b1.x,b1.y,b1.z,b1.w};
        float t[8];
        #pragma unroll
        for (int j = 0; j < 8; ++j) t[j] = (v[j] - mu) * rs * sc[j] + bi[j];
        const int kt = c0 >> 5, g = (c0 >> 3) & 3, mt = sL >> 4;
        *(bf16x8*)(XF + (((kt * 4 + mt) * 64) + g * 16 + (sL & 15)) * 8) = pack8(t);
    }

    // pack QKVG W frags (q-scale folded) while LN finishes
    bf16x8 bfr[4][2];   // [sec][kt]
    #pragma unroll
    for (int kt = 0; kt < 2; ++kt) {
        float t0[8];
        #pragma unroll
        for (int j = 0; j < 8; ++j) t0[j] = wqg[0][kt][j] * 0.17677670f;  // 1/sqrt(32)
        bfr[0][kt] = pack8(t0);
        bfr[1][kt] = pack8(wqg[1][kt]);
        bfr[2][kt] = pack8(wqg[2][kt]);
        bfr[3][kt] = pack8(wqg[3][kt]);
    }
    __syncthreads();

    // ---------------- QKVG MFMA: acc[mt][sec], rows = x-row (s or t) --------
    f32x4 acc[4][4];
    #pragma unroll
    for (int mt = 0; mt < 4; ++mt)
        #pragma unroll
        for (int sec = 0; sec < 4; ++sec) acc[mt][sec] = (f32x4){0.f, 0.f, 0.f, 0.f};
    #pragma unroll
    for (int kt = 0; kt < 2; ++kt)
        #pragma unroll
        for (int mt = 0; mt < 4; ++mt) {
            const bf16x8 a = *(const bf16x8*)(XF + ((kt * 4 + mt) * 64 + l) * 8);
            #pragma unroll
            for (int sec = 0; sec < 4; ++sec)
                acc[mt][sec] = __builtin_amdgcn_mfma_f32_16x16x32_bf16(
                    a, bfr[sec][kt], acc[mt][sec], 0, 0, 0);
        }

    // ---- issue Wout gathers now; latency hides under attention ----
    const int mt4 = wv & 3, nn2 = wv >> 2;
    const int cc  = nn2 * 16 + ln16;
    float wo[8][8];   // [kt][j]
    #pragma unroll
    for (int kt = 0; kt < 8; ++kt)
        #pragma unroll
        for (int j = 0; j < 8; ++j)
            wo[kt][j] = Wout[(kt * 32 + lg * 8 + j) * 64 + cc];

    // ---------------- register-resident attention (all lanes useful) --------
    // lane's feature f. acc rows: idx = mt*16 + lg*4 + r.
    // k = acc[.][1], v = acc[.][2] -> 16 t-partials; xor16/32 butterfly sums
    // all 64 t. q = acc[.][0] (pre-scaled), g = acc[.][3] -> 16 s outputs.
    {
        float L1 = 0.f, L2 = 0.f, L3 = 0.f, L4 = 0.f;
        float M0 = 0.f, M1 = 0.f, M2 = 0.f, M3 = 0.f, M4 = 0.f;
        #pragma unroll
        for (int mt = 0; mt < 4; ++mt)
            #pragma unroll
            for (int r = 0; r < 4; ++r) {
                const float k1 = acc[mt][1][r];
                const float vv = acc[mt][2][r];
                const float k2 = k1 * k1;
                const float k3 = k2 * k1;
                const float k4 = k2 * k2;
                L1 += k1; L2 += k2; L3 += k3; L4 += k4;
                M0 += vv;
                M1 = fmaf(k1, vv, M1);
                M2 = fmaf(k2, vv, M2);
                M3 = fmaf(k3, vv, M3);
                M4 = fmaf(k4, vv, M4);
            }
        #pragma unroll
        for (int m = 16; m <= 32; m <<= 1) {
            L1 += __shfl_xor(L1, m); L2 += __shfl_xor(L2, m);
            L3 += __shfl_xor(L3, m); L4 += __shfl_xor(L4, m);
            M0 += __shfl_xor(M0, m); M1 += __shfl_xor(M1, m);
            M2 += __shfl_xor(M2, m); M3 += __shfl_xor(M3, m);
            M4 += __shfl_xor(M4, m);
        }
        const float a4 = L4 * (1.f / 24.f), a3 = L3 * (1.f / 6.f), a2 = L2 * 0.5f;
        const float b4 = M4 * (1.f / 24.f), b3 = M3 * (1.f / 6.f), b2 = M2 * 0.5f;

        // XFo A-frag coords for feature f: kt2 = wv>>1, g2 = (wv&1)*2+(ln16>>3),
        // jj = ln16&7  (f = kt2*32 + g2*8 + jj).
        const int kt2 = wv >> 1;
        const int g2  = (wv & 1) * 2 + (ln16 >> 3);
        const int jj  = ln16 & 7;
        #pragma unroll
        for (int mt = 0; mt < 4; ++mt)
            #pragma unroll
            for (int r = 0; r < 4; ++r) {
                const float qv = acc[mt][0][r];
                const float gv = __builtin_amdgcn_rcpf(
                    1.f + __builtin_amdgcn_exp2f(acc[mt][3][r] * -1.44269504f));
                const float den = fmaf(fmaf(fmaf(fmaf(a4, qv, a3), qv, a2), qv, L1), qv, 64.f);
                const float num = fmaf(fmaf(fmaf(fmaf(b4, qv, b3), qv, b2), qv, M1), qv, M0);
                const float o   = gv * num * __builtin_amdgcn_rcpf(den);
                XFo[((kt2 * 4 + mt) * 64 + g2 * 16 + lg * 4 + r) * 8 + jj] = f2bf(o);
            }
    }

    // pack Wout frags (loads landed during attention)
    bf16x8 ofr[8];
    #pragma unroll
    for (int kt = 0; kt < 8; ++kt) ofr[kt] = pack8(wo[kt]);
    __syncthreads();

    // ---------------- out-proj (K=256) -> direct store + bias ----------------
    // wave -> (mt4 s-block, nn2 c-tile of 16). 8 kt MFMAs.
    {
        f32x4 a2v = (f32x4){0.f, 0.f, 0.f, 0.f};
        #pragma unroll
        for (int kt = 0; kt < 8; ++kt) {
            const bf16x8 afr = *(const bf16x8*)(XFo + ((kt * 4 + mt4) * 64 + l) * 8);
            a2v = __builtin_amdgcn_mfma_f32_16x16x32_bf16(afr, ofr[kt], a2v, 0, 0, 0);
        }
        const float bb = bout[cc];
        #pragma unroll
        for (int r = 0; r < 4; ++r) {
            const int s = mt4 * 16 + lg * 4 + r;
            out[(s * 128 + i) * 64 + cc] = a2v[r] + bb;
        }
    }
}

extern "C" void kernel_launch(void* const* d_in, const int* in_sizes, int n_in,
                              void* d_out, int out_size, void* d_ws, size_t ws_size,
                              hipStream_t stream) {
    (void)in_sizes; (void)n_in; (void)d_ws; (void)ws_size; (void)out_size;
    const float* msa  = (const float*)d_in[0];
    const float* ln_s = (const float*)d_in[1];
    const float* ln_b = (const float*)d_in[2];
    const float* Wqkv = (const float*)d_in[3];
    const float* Wg   = (const float*)d_in[4];
    const float* Wout = (const float*)d_in[5];
    const float* bout = (const float*)d_in[6];
    float* out = (float*)d_out;

    msa_col_attn_fused<<<dim3(128), dim3(1024), 0, stream>>>(
        msa, ln_s, ln_b, Wqkv, Wg, Wout, bout, out);
}